// Round 1
// baseline (134.120 us; speedup 1.0000x reference)
//
#include <hip/hip_runtime.h>
#include <hip/hip_bf16.h>
#include <cstdint>

typedef __hip_bfloat16 bf16;
typedef __attribute__((ext_vector_type(8))) __bf16 bf16x8;
typedef __attribute__((ext_vector_type(4))) float f32x4;

static __device__ __forceinline__ void gload_lds16(const void* g, void* l) {
  __builtin_amdgcn_global_load_lds(
      (const __attribute__((address_space(1))) uint32_t*)g,
      (__attribute__((address_space(3))) uint32_t*)l, 16, 0, 0);
}

// ---------------- prep kernels ----------------
__global__ void f32_to_bf16_kernel(const float* __restrict__ in, bf16* __restrict__ out, int n4) {
  int i = blockIdx.x * 256 + threadIdx.x;
  if (i >= n4) return;
  const float4 v = reinterpret_cast<const float4*>(in)[i];
  ushort4 o;
  o.x = __builtin_bit_cast(unsigned short, __float2bfloat16(v.x));
  o.y = __builtin_bit_cast(unsigned short, __float2bfloat16(v.y));
  o.z = __builtin_bit_cast(unsigned short, __float2bfloat16(v.z));
  o.w = __builtin_bit_cast(unsigned short, __float2bfloat16(v.w));
  reinterpret_cast<ushort4*>(out)[i] = o;
}

// in [R][C] f32 -> out [C][R] bf16 ; grid (C/32, R/32), block 256 (32x8)
__global__ void transpose_to_bf16_kernel(const float* __restrict__ in, bf16* __restrict__ out,
                                         int R, int C) {
  __shared__ float tile[32][33];
  int c0 = blockIdx.x * 32, r0 = blockIdx.y * 32;
  int tx = threadIdx.x & 31, ty = threadIdx.x >> 5;
#pragma unroll
  for (int i = 0; i < 4; ++i)
    tile[ty + i * 8][tx] = in[(size_t)(r0 + ty + i * 8) * C + c0 + tx];
  __syncthreads();
#pragma unroll
  for (int i = 0; i < 4; ++i)
    out[(size_t)(c0 + ty + i * 8) * R + r0 + tx] = __float2bfloat16(tile[tx][ty + i * 8]);
}

// ---------------- GEMM: C[M,N] = A[M,K] * Bt[N,K]^T + bias ----------------
__global__ __launch_bounds__(256)
void gemm_bt_kernel(const bf16* __restrict__ A, const bf16* __restrict__ Bt,
                    const float* __restrict__ bias, float* __restrict__ C,
                    int M, int N, int K) {
  __shared__ __align__(16) bf16 smem[2][8192];  // [A 128x32][B 128x32] per buf
  const int bcol = blockIdx.x * 128, brow = blockIdx.y * 128;
  const int t = threadIdx.x;
  const int w = t >> 6, lane = t & 63;
  const int wr = w >> 1, wc = w & 1;
  const int rr = lane & 15, kg = (lane >> 4) * 8;

  f32x4 acc[4][4];
#pragma unroll
  for (int i = 0; i < 4; ++i)
#pragma unroll
    for (int j = 0; j < 4; ++j) acc[i][j] = f32x4{0.f, 0.f, 0.f, 0.f};

  const int NK = K >> 5;

  auto stage = [&](int buf, int kt) {
    const bf16* Ab = A + (size_t)brow * K + kt * 32;
    const bf16* Bb = Bt + (size_t)bcol * K + kt * 32;
#pragma unroll
    for (int r = 0; r < 2; ++r) {
      int idx = r * 256 + t;
      int row = idx >> 2, cg = idx & 3;
      bf16* ldsA = &smem[buf][(size_t)(r * 256 + w * 64) * 8];
      bf16* ldsB = &smem[buf][4096 + (size_t)(r * 256 + w * 64) * 8];
      gload_lds16(Ab + (size_t)row * K + cg * 8, ldsA);
      gload_lds16(Bb + (size_t)row * K + cg * 8, ldsB);
    }
  };

  stage(0, 0);
  for (int kt = 0; kt < NK; ++kt) {
    __syncthreads();
    if (kt + 1 < NK) stage((kt + 1) & 1, kt + 1);
    const bf16* As = &smem[kt & 1][0];
    const bf16* Bs = &smem[kt & 1][4096];
    bf16x8 a[4], b[4];
#pragma unroll
    for (int i = 0; i < 4; ++i)
      a[i] = *reinterpret_cast<const bf16x8*>(As + (wr * 64 + i * 16 + rr) * 32 + kg);
#pragma unroll
    for (int j = 0; j < 4; ++j)
      b[j] = *reinterpret_cast<const bf16x8*>(Bs + (wc * 64 + j * 16 + rr) * 32 + kg);
#pragma unroll
    for (int i = 0; i < 4; ++i)
#pragma unroll
      for (int j = 0; j < 4; ++j)
        acc[i][j] = __builtin_amdgcn_mfma_f32_16x16x32_bf16(a[i], b[j], acc[i][j], 0, 0, 0);
  }

  const int row0 = brow + wr * 64 + (lane >> 4) * 4;
  const int col0 = bcol + wc * 64 + rr;
#pragma unroll
  for (int i = 0; i < 4; ++i)
#pragma unroll
    for (int j = 0; j < 4; ++j) {
      int gc = col0 + j * 16;
      float bv = bias[gc];
#pragma unroll
      for (int r = 0; r < 4; ++r)
        C[(size_t)(row0 + i * 16 + r) * N + gc] = acc[i][j][r] + bv;
    }
}

// ---------------- RoPE pack ----------------
__global__ void rope_pack_q_kernel(const float* __restrict__ qkv, const float* __restrict__ cosT,
                                   const float* __restrict__ sinT, bf16* __restrict__ qout) {
  int idx = blockIdx.x * 256 + threadIdx.x;  // S*32*32
  int d = idx & 31;
  int n = (idx >> 5) & 31;
  int s = idx >> 10;
  const float* base = qkv + (size_t)s * 3072 + n * 64;
  float x1 = base[d], x2 = base[d + 32];
  float c = cosT[s * 32 + d], sn = sinT[s * 32 + d];
  bf16* ob = qout + (size_t)s * 2048 + n * 64;
  ob[d] = __float2bfloat16(x1 * c - x2 * sn);
  ob[d + 32] = __float2bfloat16(x2 * c + x1 * sn);
}

__global__ void rope_pack_k_kernel(const float* __restrict__ qkv, const float* __restrict__ cosT,
                                   const float* __restrict__ sinT, bf16* __restrict__ kout) {
  int idx = blockIdx.x * 256 + threadIdx.x;  // S*8*32
  int d = idx & 31;
  int n = (idx >> 5) & 7;
  int s = idx >> 8;
  const float* base = qkv + (size_t)s * 3072 + 2048 + n * 64;
  float x1 = base[d], x2 = base[d + 32];
  float c = cosT[s * 32 + d], sn = sinT[s * 32 + d];
  bf16* ob = kout + (size_t)s * 512 + n * 64;
  ob[d] = __float2bfloat16(x1 * c - x2 * sn);
  ob[d + 32] = __float2bfloat16(x2 * c + x1 * sn);
}

// v [S][8*64] (cols 2560..3071 of qkv) -> vt [8*64][S] bf16 ; grid (8, 32) block 256
__global__ void v_transpose_kernel(const float* __restrict__ qkv, bf16* __restrict__ vt) {
  int hk = blockIdx.x, sb = blockIdx.y;
  __shared__ bf16 tile[64][65];
  int t = threadIdx.x;
#pragma unroll
  for (int p = 0; p < 16; ++p) {
    int idx = p * 256 + t;
    int si = idx >> 6, dj = idx & 63;
    tile[si][dj] = __float2bfloat16(qkv[(size_t)(sb * 64 + si) * 3072 + 2560 + hk * 64 + dj]);
  }
  __syncthreads();
#pragma unroll
  for (int p = 0; p < 16; ++p) {
    int idx = p * 256 + t;
    int di = idx >> 6, sj = idx & 63;
    vt[((size_t)hk * 64 + di) * 2048 + sb * 64 + sj] = tile[sj][di];
  }
}

// ---------------- attention ----------------
// grid (NH=32, S/64=32), block 256. Wave w owns query rows q0+w*16..+15.
// Key window tile: 192 keys starting at k0 = q0-128 (clamped loads; masked in softmax).
__global__ __launch_bounds__(256)
void attn_kernel(const bf16* __restrict__ Q, const bf16* __restrict__ Kb,
                 const bf16* __restrict__ Vt, const float* __restrict__ sinks,
                 bf16* __restrict__ aout) {
  const int h = blockIdx.x;
  const int qb = blockIdx.y;
  const int hk = h >> 2;
  const int q0 = qb * 64;
  const int k0 = q0 - 128;
  const int t = threadIdx.x, w = t >> 6, lane = t & 63;
  const int cl = lane & 15, rg = lane >> 4;
  __shared__ __align__(16) bf16 Ps[64][200];  // padded: avoids 16-way read conflicts

  // Q A-fragments (row = query, k = d)
  const int qrow = q0 + w * 16 + cl;
  bf16x8 aq[2];
#pragma unroll
  for (int ks = 0; ks < 2; ++ks)
    aq[ks] = *reinterpret_cast<const bf16x8*>(Q + (size_t)qrow * 2048 + h * 64 + ks * 32 + rg * 8);

  f32x4 acc[12];
#pragma unroll
  for (int nf = 0; nf < 12; ++nf) acc[nf] = f32x4{0.f, 0.f, 0.f, 0.f};

#pragma unroll
  for (int nf = 0; nf < 12; ++nf) {
    int key = k0 + nf * 16 + cl;
    if (key < 0) key = 0;  // garbage ok: masked below
#pragma unroll
    for (int ks = 0; ks < 2; ++ks) {
      bf16x8 bk = *reinterpret_cast<const bf16x8*>(Kb + (size_t)key * 512 + hk * 64 + ks * 32 + rg * 8);
      acc[nf] = __builtin_amdgcn_mfma_f32_16x16x32_bf16(aq[ks], bk, acc[nf], 0, 0, 0);
    }
  }

  const float sinkv = sinks[h];
  const float scale = 0.125f;  // 1/sqrt(64)
#pragma unroll
  for (int r = 0; r < 4; ++r) {
    const int rowb = w * 16 + rg * 4 + r;          // row in 64-block; qi = q0+rowb
    int cmin = rowb;                                // key >= qi-128
    if (128 - q0 > cmin) cmin = 128 - q0;           // key >= 0
    const int cmax = rowb + 128;                    // key <= qi
    float m = sinkv;
    float pv[12];
#pragma unroll
    for (int nf = 0; nf < 12; ++nf) {
      int c = nf * 16 + cl;
      float lv = (c >= cmin && c <= cmax) ? acc[nf][r] * scale : -INFINITY;
      pv[nf] = lv;
      m = fmaxf(m, lv);
    }
#pragma unroll
    for (int off = 1; off < 16; off <<= 1)
      m = fmaxf(m, __shfl_xor(m, off, 64));
    float sum = 0.f;
#pragma unroll
    for (int nf = 0; nf < 12; ++nf) {
      float p = __expf(pv[nf] - m);  // exp(-inf)=0 at masked slots
      pv[nf] = p;
      sum += p;
    }
#pragma unroll
    for (int off = 1; off < 16; off <<= 1)
      sum += __shfl_xor(sum, off, 64);
    sum += __expf(sinkv - m);  // sink column joins denominator, then is dropped
    const float inv = 1.f / sum;
#pragma unroll
    for (int nf = 0; nf < 12; ++nf)
      Ps[rowb][nf * 16 + cl] = __float2bfloat16(pv[nf] * inv);
  }

  __syncthreads();

  // PV: A = Ps (row=query, k=key), B = Vt (n=d, k=key)
  f32x4 oacc[4];
#pragma unroll
  for (int j = 0; j < 4; ++j) oacc[j] = f32x4{0.f, 0.f, 0.f, 0.f};
#pragma unroll
  for (int ks = 0; ks < 6; ++ks) {
    bf16x8 pa = *reinterpret_cast<const bf16x8*>(&Ps[w * 16 + cl][ks * 32 + rg * 8]);
    int key = k0 + ks * 32 + rg * 8;
    if (key < 0) key = 0;  // P=0 there
#pragma unroll
    for (int j = 0; j < 4; ++j) {
      bf16x8 bv = *reinterpret_cast<const bf16x8*>(Vt + ((size_t)hk * 64 + j * 16 + cl) * 2048 + key);
      oacc[j] = __builtin_amdgcn_mfma_f32_16x16x32_bf16(pa, bv, oacc[j], 0, 0, 0);
    }
  }

#pragma unroll
  for (int j = 0; j < 4; ++j)
#pragma unroll
    for (int r = 0; r < 4; ++r) {
      int gr = q0 + w * 16 + rg * 4 + r;
      int gc = h * 64 + j * 16 + cl;
      aout[(size_t)gr * 2048 + gc] = __float2bfloat16(oacc[j][r]);
    }
}

// ---------------- launch ----------------
extern "C" void kernel_launch(void* const* d_in, const int* in_sizes, int n_in,
                              void* d_out, int out_size, void* d_ws, size_t ws_size,
                              hipStream_t stream) {
  const float* x     = (const float*)d_in[0];
  const float* w1    = (const float*)d_in[1];
  const float* b1    = (const float*)d_in[2];
  const float* w2    = (const float*)d_in[3];
  const float* b2    = (const float*)d_in[4];
  const float* sinks = (const float*)d_in[5];
  const float* cosT  = (const float*)d_in[6];
  const float* sinT  = (const float*)d_in[7];
  float* out = (float*)d_out;

  char* ws = (char*)d_ws;
  // lifetime-overlaid layout (58.7 MB total)
  float* qkv = (float*)(ws);                 // [2048][3072] f32, 25165824 B
  bf16* w1t  = (bf16*)(ws + 25165824);       // [3072][2048] bf16 (dead after gemm1)
  bf16* qb   = (bf16*)(ws + 25165824);       // [2048][2048] bf16 (overlays w1t)
  bf16* xb   = (bf16*)(ws + 37748736);       // [2048][2048] bf16 (dead after gemm1)
  bf16* attn = (bf16*)(ws + 37748736);       // [2048][2048] bf16 (overlays xb)
  bf16* w2t  = (bf16*)(ws + 46137344);       // [2048][2048] bf16
  bf16* kb   = (bf16*)(ws + 54525952);       // [2048][512] bf16
  bf16* vt   = (bf16*)(ws + 56623104);       // [512][2048] bf16
  (void)in_sizes; (void)n_in; (void)out_size; (void)ws_size;

  f32_to_bf16_kernel<<<4096, 256, 0, stream>>>(x, xb, 1048576);
  transpose_to_bf16_kernel<<<dim3(96, 64), 256, 0, stream>>>(w1, w1t, 2048, 3072);
  transpose_to_bf16_kernel<<<dim3(64, 64), 256, 0, stream>>>(w2, w2t, 2048, 2048);
  gemm_bt_kernel<<<dim3(24, 16), 256, 0, stream>>>(xb, w1t, b1, qkv, 2048, 3072, 2048);
  rope_pack_q_kernel<<<8192, 256, 0, stream>>>(qkv, cosT, sinT, qb);
  rope_pack_k_kernel<<<2048, 256, 0, stream>>>(qkv, cosT, sinT, kb);
  v_transpose_kernel<<<dim3(8, 32), 256, 0, stream>>>(qkv, vt);
  attn_kernel<<<dim3(32, 32), 256, 0, stream>>>(qb, kb, vt, sinks, attn);
  gemm_bt_kernel<<<dim3(16, 16), 256, 0, stream>>>(attn, w2t, b2, out, 2048, 2048, 2048);
}

// Round 2
// 125.396 us; speedup vs baseline: 1.0696x; 1.0696x over previous
//
#include <hip/hip_runtime.h>
#include <hip/hip_bf16.h>
#include <cstdint>

typedef __hip_bfloat16 bf16;
typedef __attribute__((ext_vector_type(8))) __bf16 bf16x8;
typedef __attribute__((ext_vector_type(4))) float f32x4;

static __device__ __forceinline__ void gload_lds16(const void* g, void* l) {
  __builtin_amdgcn_global_load_lds(
      (const __attribute__((address_space(1))) uint32_t*)g,
      (__attribute__((address_space(3))) uint32_t*)l, 16, 0, 0);
}

// ---------------- prep kernels ----------------
__global__ void f32_to_bf16_kernel(const float* __restrict__ in, bf16* __restrict__ out, int n4) {
  int i = blockIdx.x * 256 + threadIdx.x;
  if (i >= n4) return;
  const float4 v = reinterpret_cast<const float4*>(in)[i];
  ushort4 o;
  o.x = __builtin_bit_cast(unsigned short, __float2bfloat16(v.x));
  o.y = __builtin_bit_cast(unsigned short, __float2bfloat16(v.y));
  o.z = __builtin_bit_cast(unsigned short, __float2bfloat16(v.z));
  o.w = __builtin_bit_cast(unsigned short, __float2bfloat16(v.w));
  reinterpret_cast<ushort4*>(out)[i] = o;
}

// in [R][C] f32 -> out [C][R] bf16 ; grid (C/32, R/32), block 256 (32x8)
__global__ void transpose_to_bf16_kernel(const float* __restrict__ in, bf16* __restrict__ out,
                                         int R, int C) {
  __shared__ float tile[32][33];
  int c0 = blockIdx.x * 32, r0 = blockIdx.y * 32;
  int tx = threadIdx.x & 31, ty = threadIdx.x >> 5;
#pragma unroll
  for (int i = 0; i < 4; ++i)
    tile[ty + i * 8][tx] = in[(size_t)(r0 + ty + i * 8) * C + c0 + tx];
  __syncthreads();
#pragma unroll
  for (int i = 0; i < 4; ++i)
    out[(size_t)(c0 + ty + i * 8) * R + r0 + tx] = __float2bfloat16(tile[tx][ty + i * 8]);
}

// ---------------- GEMM: BM=64, BN=128, BK=32, 4 waves ----------------
// MODE 0: C = A*Bt^T + bias (f32 out).  MODE 1: fused qkv epilogue
// (RoPE->qb, RoPE->kb, transpose->vt, all bf16).
// 2D-chunked XCD swizzle: nwg % 8 == 0 required (768 / 512: ok).
template <int MODE, int GXS, int GYS>
__global__ __launch_bounds__(256)
void gemm_kernel(const bf16* __restrict__ A, const bf16* __restrict__ Bt,
                 const float* __restrict__ bias, float* __restrict__ C,
                 int M, int N, int K,
                 bf16* __restrict__ qb, bf16* __restrict__ kb, bf16* __restrict__ vt,
                 const float* __restrict__ cosT, const float* __restrict__ sinT) {
  // --- XCD-chunked 2D swizzle (bijective; lin%8 picks XCD) ---
  const int lin = blockIdx.y * gridDim.x + blockIdx.x;
  const int c = lin & 7, g = lin >> 3;
  const int gcols = gridDim.x / GXS;
  const int gc = c % gcols, gr = c / gcols;
  const int bx = gc * GXS + g % GXS;
  const int by = gr * GYS + g / GXS;

  __shared__ __align__(16) bf16 smem[2][6144];  // per buf: A 64x32 (2048) + B 128x32 (4096)
  const int bcol = bx * 128, brow = by * 64;
  const int t = threadIdx.x;
  const int w = t >> 6, lane = t & 63;
  const int wr = w >> 1, wc = w & 1;
  const int rr = lane & 15, kg = (lane >> 4) * 8, rg = lane >> 4;

  f32x4 acc[2][4];
#pragma unroll
  for (int i = 0; i < 2; ++i)
#pragma unroll
    for (int j = 0; j < 4; ++j) acc[i][j] = f32x4{0.f, 0.f, 0.f, 0.f};

  const int NK = K >> 5;

  auto stage = [&](int buf, int kt) {
    const bf16* Ab = A + (size_t)brow * K + kt * 32;
    const bf16* Bb = Bt + (size_t)bcol * K + kt * 32;
    // A: 64 rows x 32 cols = 4KB = 1 gload/thread
    gload_lds16(Ab + (size_t)(t >> 2) * K + (t & 3) * 8, &smem[buf][w * 512]);
    // B: 128 rows x 32 cols = 8KB = 2 gloads/thread
#pragma unroll
    for (int r = 0; r < 2; ++r) {
      int idx = r * 256 + t;
      gload_lds16(Bb + (size_t)(idx >> 2) * K + (idx & 3) * 8,
                  &smem[buf][2048 + (r * 256 + w * 64) * 8]);
    }
  };

  stage(0, 0);
  for (int kt = 0; kt < NK; ++kt) {
    __syncthreads();
    if (kt + 1 < NK) stage((kt + 1) & 1, kt + 1);
    const bf16* As = &smem[kt & 1][0];
    const bf16* Bs = &smem[kt & 1][2048];
    bf16x8 a[2], b[4];
#pragma unroll
    for (int i = 0; i < 2; ++i)
      a[i] = *reinterpret_cast<const bf16x8*>(As + (wr * 32 + i * 16 + rr) * 32 + kg);
#pragma unroll
    for (int j = 0; j < 4; ++j)
      b[j] = *reinterpret_cast<const bf16x8*>(Bs + (wc * 64 + j * 16 + rr) * 32 + kg);
#pragma unroll
    for (int i = 0; i < 2; ++i)
#pragma unroll
      for (int j = 0; j < 4; ++j)
        acc[i][j] = __builtin_amdgcn_mfma_f32_16x16x32_bf16(a[i], b[j], acc[i][j], 0, 0, 0);
  }

  const int row0 = brow + wr * 32 + rg * 4;
  const int hb = bcol + wc * 64;  // 64-aligned global col base of this wave
  const int col0 = hb + rr;

  if constexpr (MODE == 0) {
#pragma unroll
    for (int i = 0; i < 2; ++i)
#pragma unroll
      for (int j = 0; j < 4; ++j) {
        int gcn = col0 + j * 16;
        float bv = bias[gcn];
#pragma unroll
        for (int r = 0; r < 4; ++r)
          C[(size_t)(row0 + i * 16 + r) * N + gcn] = acc[i][j][r] + bv;
      }
  } else {
    if (hb < 2048) {
      // ---- Q with RoPE: d and d+32 live in fragments j and j+2 of the same lane
#pragma unroll
      for (int i = 0; i < 2; ++i)
#pragma unroll
        for (int j = 0; j < 2; ++j) {
          const int d = j * 16 + rr;
          const float b1v = bias[hb + d], b2v = bias[hb + d + 32];
#pragma unroll
          for (int r = 0; r < 4; ++r) {
            const int s = row0 + i * 16 + r;
            const float cv = cosT[s * 32 + d], sv = sinT[s * 32 + d];
            const float x1 = acc[i][j][r] + b1v;
            const float x2 = acc[i][j + 2][r] + b2v;
            qb[(size_t)s * 2048 + hb + d] = __float2bfloat16(x1 * cv - x2 * sv);
            qb[(size_t)s * 2048 + hb + d + 32] = __float2bfloat16(x2 * cv + x1 * sv);
          }
        }
    } else if (hb < 2560) {
      // ---- K with RoPE
      const int kbase = hb - 2048;
#pragma unroll
      for (int i = 0; i < 2; ++i)
#pragma unroll
        for (int j = 0; j < 2; ++j) {
          const int d = j * 16 + rr;
          const float b1v = bias[hb + d], b2v = bias[hb + d + 32];
#pragma unroll
          for (int r = 0; r < 4; ++r) {
            const int s = row0 + i * 16 + r;
            const float cv = cosT[s * 32 + d], sv = sinT[s * 32 + d];
            const float x1 = acc[i][j][r] + b1v;
            const float x2 = acc[i][j + 2][r] + b2v;
            kb[(size_t)s * 512 + kbase + d] = __float2bfloat16(x1 * cv - x2 * sv);
            kb[(size_t)s * 512 + kbase + d + 32] = __float2bfloat16(x2 * cv + x1 * sv);
          }
        }
    } else {
      // ---- V transposed: vt[d][s], 4 consecutive s per lane -> 8B store
      const int vbase = hb - 2560;
#pragma unroll
      for (int i = 0; i < 2; ++i)
#pragma unroll
        for (int j = 0; j < 4; ++j) {
          const int vcol = vbase + j * 16 + rr;
          const float bv = bias[hb + j * 16 + rr];
          ushort4 o;
          o.x = __builtin_bit_cast(unsigned short, __float2bfloat16(acc[i][j][0] + bv));
          o.y = __builtin_bit_cast(unsigned short, __float2bfloat16(acc[i][j][1] + bv));
          o.z = __builtin_bit_cast(unsigned short, __float2bfloat16(acc[i][j][2] + bv));
          o.w = __builtin_bit_cast(unsigned short, __float2bfloat16(acc[i][j][3] + bv));
          *reinterpret_cast<ushort4*>(&vt[(size_t)vcol * 2048 + row0 + i * 16]) = o;
        }
    }
  }
}

// ---------------- attention ----------------
// grid (NH=32, S/64=32), block 256. Wave w owns query rows q0+w*16..+15.
__global__ __launch_bounds__(256)
void attn_kernel(const bf16* __restrict__ Q, const bf16* __restrict__ Kb,
                 const bf16* __restrict__ Vt, const float* __restrict__ sinks,
                 bf16* __restrict__ aout) {
  const int h = blockIdx.x;
  const int qb = blockIdx.y;
  const int hk = h >> 2;
  const int q0 = qb * 64;
  const int k0 = q0 - 128;
  const int t = threadIdx.x, w = t >> 6, lane = t & 63;
  const int cl = lane & 15, rg = lane >> 4;
  __shared__ __align__(16) bf16 Ps[64][200];

  const int qrow = q0 + w * 16 + cl;
  bf16x8 aq[2];
#pragma unroll
  for (int ks = 0; ks < 2; ++ks)
    aq[ks] = *reinterpret_cast<const bf16x8*>(Q + (size_t)qrow * 2048 + h * 64 + ks * 32 + rg * 8);

  f32x4 acc[12];
#pragma unroll
  for (int nf = 0; nf < 12; ++nf) acc[nf] = f32x4{0.f, 0.f, 0.f, 0.f};

#pragma unroll
  for (int nf = 0; nf < 12; ++nf) {
    int key = k0 + nf * 16 + cl;
    if (key < 0) key = 0;  // garbage ok: masked below
#pragma unroll
    for (int ks = 0; ks < 2; ++ks) {
      bf16x8 bk = *reinterpret_cast<const bf16x8*>(Kb + (size_t)key * 512 + hk * 64 + ks * 32 + rg * 8);
      acc[nf] = __builtin_amdgcn_mfma_f32_16x16x32_bf16(aq[ks], bk, acc[nf], 0, 0, 0);
    }
  }

  const float sinkv = sinks[h];
  const float scale = 0.125f;  // 1/sqrt(64)
#pragma unroll
  for (int r = 0; r < 4; ++r) {
    const int rowb = w * 16 + rg * 4 + r;
    int cmin = rowb;
    if (128 - q0 > cmin) cmin = 128 - q0;
    const int cmax = rowb + 128;
    float m = sinkv;
    float pv[12];
#pragma unroll
    for (int nf = 0; nf < 12; ++nf) {
      int cc = nf * 16 + cl;
      float lv = (cc >= cmin && cc <= cmax) ? acc[nf][r] * scale : -INFINITY;
      pv[nf] = lv;
      m = fmaxf(m, lv);
    }
#pragma unroll
    for (int off = 1; off < 16; off <<= 1)
      m = fmaxf(m, __shfl_xor(m, off, 64));
    float sum = 0.f;
#pragma unroll
    for (int nf = 0; nf < 12; ++nf) {
      float p = __expf(pv[nf] - m);
      pv[nf] = p;
      sum += p;
    }
#pragma unroll
    for (int off = 1; off < 16; off <<= 1)
      sum += __shfl_xor(sum, off, 64);
    sum += __expf(sinkv - m);
    const float inv = 1.f / sum;
#pragma unroll
    for (int nf = 0; nf < 12; ++nf)
      Ps[rowb][nf * 16 + cl] = __float2bfloat16(pv[nf] * inv);
  }

  __syncthreads();

  f32x4 oacc[4];
#pragma unroll
  for (int j = 0; j < 4; ++j) oacc[j] = f32x4{0.f, 0.f, 0.f, 0.f};
#pragma unroll
  for (int ks = 0; ks < 6; ++ks) {
    bf16x8 pa = *reinterpret_cast<const bf16x8*>(&Ps[w * 16 + cl][ks * 32 + rg * 8]);
    int key = k0 + ks * 32 + rg * 8;
    if (key < 0) key = 0;
#pragma unroll
    for (int j = 0; j < 4; ++j) {
      bf16x8 bv = *reinterpret_cast<const bf16x8*>(Vt + ((size_t)hk * 64 + j * 16 + cl) * 2048 + key);
      oacc[j] = __builtin_amdgcn_mfma_f32_16x16x32_bf16(pa, bv, oacc[j], 0, 0, 0);
    }
  }

#pragma unroll
  for (int j = 0; j < 4; ++j)
#pragma unroll
    for (int r = 0; r < 4; ++r) {
      int gr = q0 + w * 16 + rg * 4 + r;
      int gc = h * 64 + j * 16 + cl;
      aout[(size_t)gr * 2048 + gc] = __float2bfloat16(oacc[j][r]);
    }
}

// ---------------- launch ----------------
extern "C" void kernel_launch(void* const* d_in, const int* in_sizes, int n_in,
                              void* d_out, int out_size, void* d_ws, size_t ws_size,
                              hipStream_t stream) {
  const float* x     = (const float*)d_in[0];
  const float* w1    = (const float*)d_in[1];
  const float* b1    = (const float*)d_in[2];
  const float* w2    = (const float*)d_in[3];
  const float* b2    = (const float*)d_in[4];
  const float* sinks = (const float*)d_in[5];
  const float* cosT  = (const float*)d_in[6];
  const float* sinT  = (const float*)d_in[7];
  float* out = (float*)d_out;

  char* ws = (char*)d_ws;
  bf16* xb   = (bf16*)(ws);                  // [2048][2048] 8.0 MB
  bf16* w1t  = (bf16*)(ws + 8388608);        // [3072][2048] 12 MB
  bf16* w2t  = (bf16*)(ws + 20971520);       // [2048][2048] 8 MB
  bf16* qbuf = (bf16*)(ws + 29360128);       // [2048][2048] 8 MB
  bf16* kbuf = (bf16*)(ws + 37748736);       // [2048][512]  2 MB
  bf16* vt   = (bf16*)(ws + 39845888);       // [512][2048]  2 MB
  bf16* attn = (bf16*)(ws + 41943040);       // [2048][2048] 8 MB
  (void)in_sizes; (void)n_in; (void)out_size; (void)ws_size;

  f32_to_bf16_kernel<<<4096, 256, 0, stream>>>(x, xb, 1048576);
  transpose_to_bf16_kernel<<<dim3(96, 64), 256, 0, stream>>>(w1, w1t, 2048, 3072);
  transpose_to_bf16_kernel<<<dim3(64, 64), 256, 0, stream>>>(w2, w2t, 2048, 2048);
  // GEMM1 fused: 24 x 32 = 768 blocks (%8==0); groups 12x8
  gemm_kernel<1, 12, 8><<<dim3(24, 32), 256, 0, stream>>>(
      xb, w1t, b1, nullptr, 2048, 3072, 2048, qbuf, kbuf, vt, cosT, sinT);
  attn_kernel<<<dim3(32, 32), 256, 0, stream>>>(qbuf, kbuf, vt, sinks, attn);
  // GEMM2: 16 x 32 = 512 blocks (%8==0); groups 8x8
  gemm_kernel<0, 8, 8><<<dim3(16, 32), 256, 0, stream>>>(
      attn, w2t, b2, out, 2048, 2048, 2048, nullptr, nullptr, nullptr, nullptr, nullptr);
}

// Round 3
// 123.146 us; speedup vs baseline: 1.0891x; 1.0183x over previous
//
#include <hip/hip_runtime.h>
#include <hip/hip_bf16.h>
#include <cstdint>

typedef __hip_bfloat16 bf16;
typedef __attribute__((ext_vector_type(8))) __bf16 bf16x8;
typedef __attribute__((ext_vector_type(4))) float f32x4;

static __device__ __forceinline__ void gload_lds16(const void* g, void* l) {
  __builtin_amdgcn_global_load_lds(
      (const __attribute__((address_space(1))) uint32_t*)g,
      (__attribute__((address_space(3))) uint32_t*)l, 16, 0, 0);
}

// ---------------- prep kernels ----------------
__global__ void f32_to_bf16_kernel(const float* __restrict__ in, bf16* __restrict__ out, int n4) {
  int i = blockIdx.x * 256 + threadIdx.x;
  if (i >= n4) return;
  const float4 v = reinterpret_cast<const float4*>(in)[i];
  ushort4 o;
  o.x = __builtin_bit_cast(unsigned short, __float2bfloat16(v.x));
  o.y = __builtin_bit_cast(unsigned short, __float2bfloat16(v.y));
  o.z = __builtin_bit_cast(unsigned short, __float2bfloat16(v.z));
  o.w = __builtin_bit_cast(unsigned short, __float2bfloat16(v.w));
  reinterpret_cast<ushort4*>(out)[i] = o;
}

__global__ void transpose_to_bf16_kernel(const float* __restrict__ in, bf16* __restrict__ out,
                                         int R, int C) {
  __shared__ float tile[32][33];
  int c0 = blockIdx.x * 32, r0 = blockIdx.y * 32;
  int tx = threadIdx.x & 31, ty = threadIdx.x >> 5;
#pragma unroll
  for (int i = 0; i < 4; ++i)
    tile[ty + i * 8][tx] = in[(size_t)(r0 + ty + i * 8) * C + c0 + tx];
  __syncthreads();
#pragma unroll
  for (int i = 0; i < 4; ++i)
    out[(size_t)(c0 + ty + i * 8) * R + r0 + tx] = __float2bfloat16(tile[tx][ty + i * 8]);
}

// ---------------- GEMM1: 8-phase pipelined, BM=128 BN=256 BK=64, 8 waves ----------------
// 3-deep LDS buffering (A 3x16KB + B 3x32KB = 144KB dynamic), stage 2 tiles ahead,
// counted vmcnt(6) once per K-tile, T2 XOR swizzle (pre-swizzled global source),
// T5 setprio around MFMA. Fused epilogue: RoPE->qb, RoPE->kb, V^T->vt (bf16).
__global__ __launch_bounds__(512, 1)
void gemm1_8ph_kernel(const bf16* __restrict__ A, const bf16* __restrict__ Bt,
                      const float* __restrict__ bias,
                      bf16* __restrict__ qb, bf16* __restrict__ kb, bf16* __restrict__ vt,
                      const float* __restrict__ cosT, const float* __restrict__ sinT) {
  extern __shared__ __align__(16) char smem[];
  constexpr int K = 2048, NK = 32;
  // XCD-chunked bijective swizzle: 192 blocks, 24 per XCD
  const int lin = blockIdx.x;
  const int wgid = (lin & 7) * 24 + (lin >> 3);
  const int bx = wgid % 12, by = wgid / 12;
  const int brow = by * 128, bcol = bx * 256;
  const int t = threadIdx.x, lane = t & 63, w = t >> 6;
  const int wr = w >> 2, wc = w & 3;           // 2 (M) x 4 (N) waves
  const int rr = lane & 15, rg = lane >> 4;

  char* Ab = smem;              // 3 x 16384 B  : [128 rows][8 chunks of 16B]
  char* Bb = smem + 49152;      // 3 x 32768 B  : [256 rows][8 chunks of 16B]

  auto stageA = [&](int kt, int half) {
    const int idx = t;                       // 512 chunks per half
    const int row = half * 64 + (idx >> 3);
    const int cg = (idx & 7) ^ (row & 7);    // inverse-swizzled source
    gload_lds16(A + (size_t)(brow + row) * K + kt * 64 + cg * 8,
                Ab + (size_t)(kt % 3) * 16384 + (half * 512 + (t & ~63)) * 16);
  };
  auto stageB = [&](int kt, int half) {
#pragma unroll
    for (int r2 = 0; r2 < 2; ++r2) {
      const int idx = r2 * 512 + t;          // 1024 chunks per half
      const int row = half * 128 + (idx >> 3);
      const int cg = (idx & 7) ^ (row & 7);
      gload_lds16(Bt + (size_t)(bcol + row) * K + kt * 64 + cg * 8,
                  Bb + (size_t)(kt % 3) * 32768 + (half * 1024 + r2 * 512 + (t & ~63)) * 16);
    }
  };

  f32x4 acc[4][4];
#pragma unroll
  for (int i = 0; i < 4; ++i)
#pragma unroll
    for (int j = 0; j < 4; ++j) acc[i][j] = f32x4{0.f, 0.f, 0.f, 0.f};

  // prologue: stage tiles 0 and 1 (12 gloads/thread), wait for tile 0 (6 newer in flight)
  stageA(0, 0); stageB(0, 0); stageA(0, 1); stageB(0, 1);
  stageA(1, 0); stageB(1, 0); stageA(1, 1); stageB(1, 1);
  asm volatile("s_waitcnt vmcnt(6)" ::: "memory");
  __builtin_amdgcn_s_barrier();

  for (int kt = 0; kt < NK; ++kt) {
    const char* Ar = Ab + (size_t)(kt % 3) * 16384;
    const char* Br = Bb + (size_t)(kt % 3) * 32768;
#pragma unroll
    for (int q = 0; q < 4; ++q) {
      const int ih = (q >> 1) * 2, jh = (q & 1) * 2;
      bf16x8 af[2][2], bfr[2][2];
#pragma unroll
      for (int ii = 0; ii < 2; ++ii)
#pragma unroll
        for (int ks = 0; ks < 2; ++ks) {
          const int row = wr * 64 + (ih + ii) * 16 + rr;
          const int c = ks * 4 + rg;
          af[ii][ks] = *reinterpret_cast<const bf16x8*>(
              Ar + row * 128 + ((c ^ (row & 7)) * 16));
        }
#pragma unroll
      for (int jj = 0; jj < 2; ++jj)
#pragma unroll
        for (int ks = 0; ks < 2; ++ks) {
          const int row = wc * 64 + (jh + jj) * 16 + rr;
          const int c = ks * 4 + rg;
          bfr[jj][ks] = *reinterpret_cast<const bf16x8*>(
              Br + row * 128 + ((c ^ (row & 7)) * 16));
        }
      if (kt + 2 < NK) {
        if (q == 0) { stageA(kt + 2, 0); stageB(kt + 2, 0); }
        else if (q == 1) { stageA(kt + 2, 1); stageB(kt + 2, 1); }
      }
      asm volatile("s_waitcnt lgkmcnt(0)" ::: "memory");
      __builtin_amdgcn_sched_barrier(0);
      __builtin_amdgcn_s_setprio(1);
#pragma unroll
      for (int ii = 0; ii < 2; ++ii)
#pragma unroll
        for (int jj = 0; jj < 2; ++jj)
#pragma unroll
          for (int ks = 0; ks < 2; ++ks)
            acc[ih + ii][jh + jj] = __builtin_amdgcn_mfma_f32_16x16x32_bf16(
                af[ii][ks], bfr[jj][ks], acc[ih + ii][jh + jj], 0, 0, 0);
      __builtin_amdgcn_s_setprio(0);
      if (q == 3 && kt + 1 < NK) {
        if (kt + 2 < NK) asm volatile("s_waitcnt vmcnt(6)" ::: "memory");
        else             asm volatile("s_waitcnt vmcnt(0)" ::: "memory");
      }
      if (kt + 1 < NK || q < 3) __builtin_amdgcn_s_barrier();
    }
  }

  // ---- fused epilogue ----
  const int hb = bcol + wc * 64;
  if (hb < 2048) {
#pragma unroll
    for (int i = 0; i < 4; ++i)
#pragma unroll
      for (int j = 0; j < 2; ++j) {
        const int d = j * 16 + rr;
        const float b1v = bias[hb + d], b2v = bias[hb + d + 32];
#pragma unroll
        for (int r = 0; r < 4; ++r) {
          const int s = brow + wr * 64 + i * 16 + rg * 4 + r;
          const float cv = cosT[s * 32 + d], sv = sinT[s * 32 + d];
          const float x1 = acc[i][j][r] + b1v;
          const float x2 = acc[i][j + 2][r] + b2v;
          qb[(size_t)s * 2048 + hb + d] = __float2bfloat16(x1 * cv - x2 * sv);
          qb[(size_t)s * 2048 + hb + d + 32] = __float2bfloat16(x2 * cv + x1 * sv);
        }
      }
  } else if (hb < 2560) {
    const int kbase = hb - 2048;
#pragma unroll
    for (int i = 0; i < 4; ++i)
#pragma unroll
      for (int j = 0; j < 2; ++j) {
        const int d = j * 16 + rr;
        const float b1v = bias[hb + d], b2v = bias[hb + d + 32];
#pragma unroll
        for (int r = 0; r < 4; ++r) {
          const int s = brow + wr * 64 + i * 16 + rg * 4 + r;
          const float cv = cosT[s * 32 + d], sv = sinT[s * 32 + d];
          const float x1 = acc[i][j][r] + b1v;
          const float x2 = acc[i][j + 2][r] + b2v;
          kb[(size_t)s * 512 + kbase + d] = __float2bfloat16(x1 * cv - x2 * sv);
          kb[(size_t)s * 512 + kbase + d + 32] = __float2bfloat16(x2 * cv + x1 * sv);
        }
      }
  } else {
    const int vbase = hb - 2560;
#pragma unroll
    for (int i = 0; i < 4; ++i)
#pragma unroll
      for (int j = 0; j < 4; ++j) {
        const int vcol = vbase + j * 16 + rr;
        const float bv = bias[hb + j * 16 + rr];
        ushort4 o;
        o.x = __builtin_bit_cast(unsigned short, __float2bfloat16(acc[i][j][0] + bv));
        o.y = __builtin_bit_cast(unsigned short, __float2bfloat16(acc[i][j][1] + bv));
        o.z = __builtin_bit_cast(unsigned short, __float2bfloat16(acc[i][j][2] + bv));
        o.w = __builtin_bit_cast(unsigned short, __float2bfloat16(acc[i][j][3] + bv));
        *reinterpret_cast<ushort4*>(
            &vt[(size_t)vcol * 2048 + brow + wr * 64 + i * 16 + rg * 4]) = o;
      }
  }
}

// ---------------- GEMM2: proven 128x128 BK=32 2-phase (R1 structure) ----------------
__global__ __launch_bounds__(256)
void gemm_bt_kernel(const bf16* __restrict__ A, const bf16* __restrict__ Bt,
                    const float* __restrict__ bias, float* __restrict__ C,
                    int M, int N, int K) {
  __shared__ __align__(16) bf16 smem[2][8192];
  const int bcol = blockIdx.x * 128, brow = blockIdx.y * 128;
  const int t = threadIdx.x;
  const int w = t >> 6, lane = t & 63;
  const int wr = w >> 1, wc = w & 1;
  const int rr = lane & 15, kg = (lane >> 4) * 8;

  f32x4 acc[4][4];
#pragma unroll
  for (int i = 0; i < 4; ++i)
#pragma unroll
    for (int j = 0; j < 4; ++j) acc[i][j] = f32x4{0.f, 0.f, 0.f, 0.f};

  const int NK = K >> 5;

  auto stage = [&](int buf, int kt) {
    const bf16* Ab = A + (size_t)brow * K + kt * 32;
    const bf16* Bb = Bt + (size_t)bcol * K + kt * 32;
#pragma unroll
    for (int r = 0; r < 2; ++r) {
      int idx = r * 256 + t;
      int row = idx >> 2, cg = idx & 3;
      bf16* ldsA = &smem[buf][(size_t)(r * 256 + w * 64) * 8];
      bf16* ldsB = &smem[buf][4096 + (size_t)(r * 256 + w * 64) * 8];
      gload_lds16(Ab + (size_t)row * K + cg * 8, ldsA);
      gload_lds16(Bb + (size_t)row * K + cg * 8, ldsB);
    }
  };

  stage(0, 0);
  for (int kt = 0; kt < NK; ++kt) {
    __syncthreads();
    if (kt + 1 < NK) stage((kt + 1) & 1, kt + 1);
    const bf16* As = &smem[kt & 1][0];
    const bf16* Bs = &smem[kt & 1][4096];
    bf16x8 a[4], b[4];
#pragma unroll
    for (int i = 0; i < 4; ++i)
      a[i] = *reinterpret_cast<const bf16x8*>(As + (wr * 64 + i * 16 + rr) * 32 + kg);
#pragma unroll
    for (int j = 0; j < 4; ++j)
      b[j] = *reinterpret_cast<const bf16x8*>(Bs + (wc * 64 + j * 16 + rr) * 32 + kg);
#pragma unroll
    for (int i = 0; i < 4; ++i)
#pragma unroll
      for (int j = 0; j < 4; ++j)
        acc[i][j] = __builtin_amdgcn_mfma_f32_16x16x32_bf16(a[i], b[j], acc[i][j], 0, 0, 0);
  }

  const int row0 = brow + wr * 64 + (lane >> 4) * 4;
  const int col0 = bcol + wc * 64 + rr;
#pragma unroll
  for (int i = 0; i < 4; ++i)
#pragma unroll
    for (int j = 0; j < 4; ++j) {
      int gc = col0 + j * 16;
      float bv = bias[gc];
#pragma unroll
      for (int r = 0; r < 4; ++r)
        C[(size_t)(row0 + i * 16 + r) * N + gc] = acc[i][j][r] + bv;
    }
}

// ---------------- attention ----------------
__global__ __launch_bounds__(256)
void attn_kernel(const bf16* __restrict__ Q, const bf16* __restrict__ Kb,
                 const bf16* __restrict__ Vt, const float* __restrict__ sinks,
                 bf16* __restrict__ aout) {
  const int h = blockIdx.x;
  const int qb = blockIdx.y;
  const int hk = h >> 2;
  const int q0 = qb * 64;
  const int k0 = q0 - 128;
  const int t = threadIdx.x, w = t >> 6, lane = t & 63;
  const int cl = lane & 15, rg = lane >> 4;
  __shared__ __align__(16) bf16 Ps[64][200];

  const int qrow = q0 + w * 16 + cl;
  bf16x8 aq[2];
#pragma unroll
  for (int ks = 0; ks < 2; ++ks)
    aq[ks] = *reinterpret_cast<const bf16x8*>(Q + (size_t)qrow * 2048 + h * 64 + ks * 32 + rg * 8);

  f32x4 acc[12];
#pragma unroll
  for (int nf = 0; nf < 12; ++nf) acc[nf] = f32x4{0.f, 0.f, 0.f, 0.f};

#pragma unroll
  for (int nf = 0; nf < 12; ++nf) {
    int key = k0 + nf * 16 + cl;
    if (key < 0) key = 0;
#pragma unroll
    for (int ks = 0; ks < 2; ++ks) {
      bf16x8 bk = *reinterpret_cast<const bf16x8*>(Kb + (size_t)key * 512 + hk * 64 + ks * 32 + rg * 8);
      acc[nf] = __builtin_amdgcn_mfma_f32_16x16x32_bf16(aq[ks], bk, acc[nf], 0, 0, 0);
    }
  }

  const float sinkv = sinks[h];
  const float scale = 0.125f;
#pragma unroll
  for (int r = 0; r < 4; ++r) {
    const int rowb = w * 16 + rg * 4 + r;
    int cmin = rowb;
    if (128 - q0 > cmin) cmin = 128 - q0;
    const int cmax = rowb + 128;
    float m = sinkv;
    float pv[12];
#pragma unroll
    for (int nf = 0; nf < 12; ++nf) {
      int cc = nf * 16 + cl;
      float lv = (cc >= cmin && cc <= cmax) ? acc[nf][r] * scale : -INFINITY;
      pv[nf] = lv;
      m = fmaxf(m, lv);
    }
#pragma unroll
    for (int off = 1; off < 16; off <<= 1)
      m = fmaxf(m, __shfl_xor(m, off, 64));
    float sum = 0.f;
#pragma unroll
    for (int nf = 0; nf < 12; ++nf) {
      float p = __expf(pv[nf] - m);
      pv[nf] = p;
      sum += p;
    }
#pragma unroll
    for (int off = 1; off < 16; off <<= 1)
      sum += __shfl_xor(sum, off, 64);
    sum += __expf(sinkv - m);
    const float inv = 1.f / sum;
#pragma unroll
    for (int nf = 0; nf < 12; ++nf)
      Ps[rowb][nf * 16 + cl] = __float2bfloat16(pv[nf] * inv);
  }

  __syncthreads();

  f32x4 oacc[4];
#pragma unroll
  for (int j = 0; j < 4; ++j) oacc[j] = f32x4{0.f, 0.f, 0.f, 0.f};
#pragma unroll
  for (int ks = 0; ks < 6; ++ks) {
    bf16x8 pa = *reinterpret_cast<const bf16x8*>(&Ps[w * 16 + cl][ks * 32 + rg * 8]);
    int key = k0 + ks * 32 + rg * 8;
    if (key < 0) key = 0;
#pragma unroll
    for (int j = 0; j < 4; ++j) {
      bf16x8 bv = *reinterpret_cast<const bf16x8*>(Vt + ((size_t)hk * 64 + j * 16 + cl) * 2048 + key);
      oacc[j] = __builtin_amdgcn_mfma_f32_16x16x32_bf16(pa, bv, oacc[j], 0, 0, 0);
    }
  }

#pragma unroll
  for (int j = 0; j < 4; ++j)
#pragma unroll
    for (int r = 0; r < 4; ++r) {
      int gr = q0 + w * 16 + rg * 4 + r;
      int gc = h * 64 + j * 16 + cl;
      aout[(size_t)gr * 2048 + gc] = __float2bfloat16(oacc[j][r]);
    }
}

// ---------------- launch ----------------
extern "C" void kernel_launch(void* const* d_in, const int* in_sizes, int n_in,
                              void* d_out, int out_size, void* d_ws, size_t ws_size,
                              hipStream_t stream) {
  const float* x     = (const float*)d_in[0];
  const float* w1    = (const float*)d_in[1];
  const float* b1    = (const float*)d_in[2];
  const float* w2    = (const float*)d_in[3];
  const float* b2    = (const float*)d_in[4];
  const float* sinks = (const float*)d_in[5];
  const float* cosT  = (const float*)d_in[6];
  const float* sinT  = (const float*)d_in[7];
  float* out = (float*)d_out;

  char* ws = (char*)d_ws;
  bf16* xb   = (bf16*)(ws);                  // [2048][2048] 8 MB
  bf16* w1t  = (bf16*)(ws + 8388608);        // [3072][2048] 12 MB
  bf16* w2t  = (bf16*)(ws + 20971520);       // [2048][2048] 8 MB
  bf16* qbuf = (bf16*)(ws + 29360128);       // [2048][2048] 8 MB
  bf16* kbuf = (bf16*)(ws + 37748736);       // [2048][512]  2 MB
  bf16* vt   = (bf16*)(ws + 39845888);       // [512][2048]  2 MB
  bf16* attn = (bf16*)(ws + 41943040);       // [2048][2048] 8 MB
  (void)in_sizes; (void)n_in; (void)out_size; (void)ws_size;

  f32_to_bf16_kernel<<<4096, 256, 0, stream>>>(x, xb, 1048576);
  transpose_to_bf16_kernel<<<dim3(96, 64), 256, 0, stream>>>(w1, w1t, 2048, 3072);
  transpose_to_bf16_kernel<<<dim3(64, 64), 256, 0, stream>>>(w2, w2t, 2048, 2048);
  // GEMM1: 8-phase pipelined, 192 blocks, 144 KB dynamic LDS
  gemm1_8ph_kernel<<<192, 512, 147456, stream>>>(xb, w1t, b1, qbuf, kbuf, vt, cosT, sinT);
  attn_kernel<<<dim3(32, 32), 256, 0, stream>>>(qbuf, kbuf, vt, sinks, attn);
  // GEMM2: proven R1 config, 256 blocks
  gemm_bt_kernel<<<dim3(16, 16), 256, 0, stream>>>(attn, w2t, b2, out, 2048, 2048, 2048);
}

// Round 4
// 109.156 us; speedup vs baseline: 1.2287x; 1.1282x over previous
//
#include <hip/hip_runtime.h>
#include <hip/hip_bf16.h>
#include <cstdint>

typedef __hip_bfloat16 bf16;
typedef __attribute__((ext_vector_type(8))) __bf16 bf16x8;
typedef __attribute__((ext_vector_type(4))) float f32x4;

static __device__ __forceinline__ void gload_lds16(const void* g, void* l) {
  __builtin_amdgcn_global_load_lds(
      (const __attribute__((address_space(1))) uint32_t*)g,
      (__attribute__((address_space(3))) uint32_t*)l, 16, 0, 0);
}

// ---------------- prep kernels ----------------
__global__ void f32_to_bf16_kernel(const float* __restrict__ in, bf16* __restrict__ out, int n4) {
  int i = blockIdx.x * 256 + threadIdx.x;
  if (i >= n4) return;
  const float4 v = reinterpret_cast<const float4*>(in)[i];
  ushort4 o;
  o.x = __builtin_bit_cast(unsigned short, __float2bfloat16(v.x));
  o.y = __builtin_bit_cast(unsigned short, __float2bfloat16(v.y));
  o.z = __builtin_bit_cast(unsigned short, __float2bfloat16(v.z));
  o.w = __builtin_bit_cast(unsigned short, __float2bfloat16(v.w));
  reinterpret_cast<ushort4*>(out)[i] = o;
}

__global__ void transpose_to_bf16_kernel(const float* __restrict__ in, bf16* __restrict__ out,
                                         int R, int C) {
  __shared__ float tile[32][33];
  int c0 = blockIdx.x * 32, r0 = blockIdx.y * 32;
  int tx = threadIdx.x & 31, ty = threadIdx.x >> 5;
#pragma unroll
  for (int i = 0; i < 4; ++i)
    tile[ty + i * 8][tx] = in[(size_t)(r0 + ty + i * 8) * C + c0 + tx];
  __syncthreads();
#pragma unroll
  for (int i = 0; i < 4; ++i)
    out[(size_t)(c0 + ty + i * 8) * R + r0 + tx] = __float2bfloat16(tile[tx][ty + i * 8]);
}

// ---------------- RoPE in-place (bf16), thread = 8 d-pairs ----------------
template <int NH, int SSHIFT>
__global__ void rope_kernel(bf16* __restrict__ buf, const float* __restrict__ cosT,
                            const float* __restrict__ sinT) {
  const int idx = blockIdx.x * 256 + threadIdx.x;
  const int c = idx & 3;
  const int h = (idx >> 2) & (NH - 1);
  const int s = idx >> SSHIFT;
  bf16* p = buf + (size_t)s * (NH * 64) + h * 64 + c * 8;
  bf16x8 v1 = *reinterpret_cast<bf16x8*>(p);
  bf16x8 v2 = *reinterpret_cast<bf16x8*>(p + 32);
  const float4 c0 = *reinterpret_cast<const float4*>(&cosT[s * 32 + c * 8]);
  const float4 c1 = *reinterpret_cast<const float4*>(&cosT[s * 32 + c * 8 + 4]);
  const float4 s0 = *reinterpret_cast<const float4*>(&sinT[s * 32 + c * 8]);
  const float4 s1 = *reinterpret_cast<const float4*>(&sinT[s * 32 + c * 8 + 4]);
  const float cs[8] = {c0.x, c0.y, c0.z, c0.w, c1.x, c1.y, c1.z, c1.w};
  const float sn[8] = {s0.x, s0.y, s0.z, s0.w, s1.x, s1.y, s1.z, s1.w};
  bf16x8 o1, o2;
#pragma unroll
  for (int e = 0; e < 8; ++e) {
    const float x1 = (float)v1[e], x2 = (float)v2[e];
    o1[e] = (__bf16)(x1 * cs[e] - x2 * sn[e]);
    o2[e] = (__bf16)(x2 * cs[e] + x1 * sn[e]);
  }
  *reinterpret_cast<bf16x8*>(p) = o1;
  *reinterpret_cast<bf16x8*>(p + 32) = o2;
}

// ---------------- GEMM1: BM=128 BN=192 BK=64, 8 waves, 3-deep pipeline ----------------
// Per ks-phase: 7 ds_read_b128 (each fragment once) -> 12 MFMA (ratio fixed vs R3).
// Epilogue: raw q (bias), raw k (bias), V^T (bias) all bf16. RoPE applied later.
__global__ __launch_bounds__(512, 1)
void gemm1_kernel(const bf16* __restrict__ A, const bf16* __restrict__ Bt,
                  const float* __restrict__ bias,
                  bf16* __restrict__ qb, bf16* __restrict__ kb, bf16* __restrict__ vt) {
  extern __shared__ __align__(16) char smem[];
  constexpr int K = 2048, NK = 32;
  // 256 blocks, 32 per XCD, bijective chunked swizzle
  const int lin = blockIdx.x;
  const int wgid = (lin & 7) * 32 + (lin >> 3);
  const int bx = wgid & 15, by = wgid >> 4;
  const int brow = by * 128, bcol = bx * 192;
  const int t = threadIdx.x, lane = t & 63, w = t >> 6;
  const int wr = w >> 2, wc = w & 3;  // 2 (M) x 4 (N)
  const int rr = lane & 15, rg = lane >> 4;

  char* Ab = smem;              // 3 x 16384 : [128 rows][8 x 16B]
  char* Bb = smem + 49152;      // 3 x 24576 : [192 rows][8 x 16B]

  auto stageA = [&](int kt) {
#pragma unroll
    for (int p = 0; p < 2; ++p) {
      const int idx = p * 512 + t;
      const int row = idx >> 3;
      const int cg = (idx & 7) ^ (row & 7);
      gload_lds16(A + (size_t)(brow + row) * K + kt * 64 + cg * 8,
                  Ab + (size_t)(kt % 3) * 16384 + (p * 512 + (t & ~63)) * 16);
    }
  };
  auto stageB = [&](int kt) {
#pragma unroll
    for (int p = 0; p < 3; ++p) {
      const int idx = p * 512 + t;
      const int row = idx >> 3;
      const int cg = (idx & 7) ^ (row & 7);
      gload_lds16(Bt + (size_t)(bcol + row) * K + kt * 64 + cg * 8,
                  Bb + (size_t)(kt % 3) * 24576 + (p * 512 + (t & ~63)) * 16);
    }
  };

  f32x4 acc[4][3];
#pragma unroll
  for (int i = 0; i < 4; ++i)
#pragma unroll
    for (int j = 0; j < 3; ++j) acc[i][j] = f32x4{0.f, 0.f, 0.f, 0.f};

  stageA(0); stageB(0); stageA(1); stageB(1);
  asm volatile("s_waitcnt vmcnt(5)" ::: "memory");
  __builtin_amdgcn_s_barrier();

  for (int kt = 0; kt < NK; ++kt) {
    const char* Ar = Ab + (size_t)(kt % 3) * 16384;
    const char* Br = Bb + (size_t)(kt % 3) * 24576;
#pragma unroll
    for (int ks = 0; ks < 2; ++ks) {
      bf16x8 af[4], bfr[3];
      const int c = ks * 4 + rg;
#pragma unroll
      for (int i = 0; i < 4; ++i) {
        const int row = wr * 64 + i * 16 + rr;
        af[i] = *reinterpret_cast<const bf16x8*>(Ar + row * 128 + ((c ^ (row & 7)) * 16));
      }
#pragma unroll
      for (int j = 0; j < 3; ++j) {
        const int row = wc * 48 + j * 16 + rr;
        bfr[j] = *reinterpret_cast<const bf16x8*>(Br + row * 128 + ((c ^ (row & 7)) * 16));
      }
      if (kt + 2 < NK) {
        if (ks == 0) stageA(kt + 2);
        else         stageB(kt + 2);
      }
      asm volatile("s_waitcnt lgkmcnt(0)" ::: "memory");
      __builtin_amdgcn_sched_barrier(0);
      __builtin_amdgcn_s_setprio(1);
#pragma unroll
      for (int i = 0; i < 4; ++i)
#pragma unroll
        for (int j = 0; j < 3; ++j)
          acc[i][j] = __builtin_amdgcn_mfma_f32_16x16x32_bf16(af[i], bfr[j], acc[i][j], 0, 0, 0);
      __builtin_amdgcn_s_setprio(0);
      if (ks == 1) {
        if (kt + 2 < NK)      asm volatile("s_waitcnt vmcnt(5)" ::: "memory");
        else if (kt + 1 < NK) asm volatile("s_waitcnt vmcnt(0)" ::: "memory");
      }
      if (kt + 1 < NK || ks == 0) __builtin_amdgcn_s_barrier();
    }
  }

  // ---- epilogue: per-16-col fragment region dispatch ----
#pragma unroll
  for (int j = 0; j < 3; ++j) {
    const int gcf = bcol + wc * 48 + j * 16;   // 16-aligned fragment col base
    const int gc = gcf + rr;
    const float bv = bias[gc];
    if (gcf < 2048) {            // raw Q
#pragma unroll
      for (int i = 0; i < 4; ++i) {
        const int s0 = brow + wr * 64 + i * 16 + rg * 4;
#pragma unroll
        for (int r = 0; r < 4; ++r)
          qb[(size_t)(s0 + r) * 2048 + gc] = __float2bfloat16(acc[i][j][r] + bv);
      }
    } else if (gcf < 2560) {     // raw K
      const int kc = gc - 2048;
#pragma unroll
      for (int i = 0; i < 4; ++i) {
        const int s0 = brow + wr * 64 + i * 16 + rg * 4;
#pragma unroll
        for (int r = 0; r < 4; ++r)
          kb[(size_t)(s0 + r) * 512 + kc] = __float2bfloat16(acc[i][j][r] + bv);
      }
    } else {                     // V^T
      const int vcol = gc - 2560;
#pragma unroll
      for (int i = 0; i < 4; ++i) {
        ushort4 o;
        o.x = __builtin_bit_cast(unsigned short, __float2bfloat16(acc[i][j][0] + bv));
        o.y = __builtin_bit_cast(unsigned short, __float2bfloat16(acc[i][j][1] + bv));
        o.z = __builtin_bit_cast(unsigned short, __float2bfloat16(acc[i][j][2] + bv));
        o.w = __builtin_bit_cast(unsigned short, __float2bfloat16(acc[i][j][3] + bv));
        *reinterpret_cast<ushort4*>(
            &vt[(size_t)vcol * 2048 + brow + wr * 64 + i * 16 + rg * 4]) = o;
      }
    }
  }
}

// ---------------- GEMM2: BM=128 BN=128 BK=64, 8 waves (wave-split-K), 3-deep ----------------
__global__ __launch_bounds__(512, 1)
void gemm2_kernel(const bf16* __restrict__ A, const bf16* __restrict__ Bt,
                  const float* __restrict__ bias, float* __restrict__ C) {
  extern __shared__ __align__(16) char smem[];
  constexpr int K = 2048, NK = 32;
  const int lin = blockIdx.x;
  const int wgid = (lin & 7) * 32 + (lin >> 3);
  const int bx = wgid & 15, by = wgid >> 4;
  const int brow = by * 128, bcol = bx * 128;
  const int t = threadIdx.x, lane = t & 63, w = t >> 6;
  const int wr = (w & 3) >> 1, wc = w & 1, khalf = w >> 2;  // waves 0-3: k-half 0; 4-7: half 1
  const int rr = lane & 15, rg = lane >> 4;

  char* Ab = smem;              // 3 x 16384
  char* Bb = smem + 49152;      // 3 x 16384

  auto stage = [&](int kt) {
#pragma unroll
    for (int p = 0; p < 2; ++p) {
      const int idx = p * 512 + t;
      const int row = idx >> 3;
      const int cg = (idx & 7) ^ (row & 7);
      gload_lds16(A + (size_t)(brow + row) * K + kt * 64 + cg * 8,
                  Ab + (size_t)(kt % 3) * 16384 + (p * 512 + (t & ~63)) * 16);
      gload_lds16(Bt + (size_t)(bcol + row) * K + kt * 64 + cg * 8,
                  Bb + (size_t)(kt % 3) * 16384 + (p * 512 + (t & ~63)) * 16);
    }
  };

  f32x4 acc[4][4];
#pragma unroll
  for (int i = 0; i < 4; ++i)
#pragma unroll
    for (int j = 0; j < 4; ++j) acc[i][j] = f32x4{0.f, 0.f, 0.f, 0.f};

  stage(0); stage(1);
  asm volatile("s_waitcnt vmcnt(4)" ::: "memory");
  __builtin_amdgcn_s_barrier();

  for (int kt = 0; kt < NK; ++kt) {
    const char* Ar = Ab + (size_t)(kt % 3) * 16384;
    const char* Br = Bb + (size_t)(kt % 3) * 16384;
    bf16x8 af[4], bfr[4];
    const int c = khalf * 4 + rg;
#pragma unroll
    for (int i = 0; i < 4; ++i) {
      const int row = wr * 64 + i * 16 + rr;
      af[i] = *reinterpret_cast<const bf16x8*>(Ar + row * 128 + ((c ^ (row & 7)) * 16));
    }
#pragma unroll
    for (int j = 0; j < 4; ++j) {
      const int row = wc * 64 + j * 16 + rr;
      bfr[j] = *reinterpret_cast<const bf16x8*>(Br + row * 128 + ((c ^ (row & 7)) * 16));
    }
    if (kt + 2 < NK) stage(kt + 2);
    asm volatile("s_waitcnt lgkmcnt(0)" ::: "memory");
    __builtin_amdgcn_sched_barrier(0);
    __builtin_amdgcn_s_setprio(1);
#pragma unroll
    for (int i = 0; i < 4; ++i)
#pragma unroll
      for (int j = 0; j < 4; ++j)
        acc[i][j] = __builtin_amdgcn_mfma_f32_16x16x32_bf16(af[i], bfr[j], acc[i][j], 0, 0, 0);
    __builtin_amdgcn_s_setprio(0);
    if (kt + 2 < NK)      asm volatile("s_waitcnt vmcnt(4)" ::: "memory");
    else if (kt + 1 < NK) asm volatile("s_waitcnt vmcnt(0)" ::: "memory");
    if (kt + 1 < NK) __builtin_amdgcn_s_barrier();
  }

  // ---- cross-wave K reduction via LDS, then epilogue by waves 0-3 ----
  __syncthreads();
  float* red = (float*)smem;   // 4 waves x 64 lanes x 64 f32 = 64 KB
  if (w >= 4) {
#pragma unroll
    for (int i = 0; i < 4; ++i)
#pragma unroll
      for (int j = 0; j < 4; ++j)
        *reinterpret_cast<f32x4*>(&red[(w - 4) * 4096 + (i * 4 + j) * 256 + lane * 4]) = acc[i][j];
  }
  __syncthreads();
  if (w < 4) {
#pragma unroll
    for (int i = 0; i < 4; ++i)
#pragma unroll
      for (int j = 0; j < 4; ++j) {
        const f32x4 o = *reinterpret_cast<const f32x4*>(&red[w * 4096 + (i * 4 + j) * 256 + lane * 4]);
        const int gc = bcol + wc * 64 + j * 16 + rr;
        const float bv = bias[gc];
        const int r0 = brow + wr * 64 + i * 16 + rg * 4;
#pragma unroll
        for (int r = 0; r < 4; ++r)
          C[(size_t)(r0 + r) * 2048 + gc] = acc[i][j][r] + o[r] + bv;
      }
  }
}

// ---------------- attention (unchanged, proven) ----------------
__global__ __launch_bounds__(256)
void attn_kernel(const bf16* __restrict__ Q, const bf16* __restrict__ Kb,
                 const bf16* __restrict__ Vt, const float* __restrict__ sinks,
                 bf16* __restrict__ aout) {
  const int h = blockIdx.x;
  const int qb = blockIdx.y;
  const int hk = h >> 2;
  const int q0 = qb * 64;
  const int k0 = q0 - 128;
  const int t = threadIdx.x, w = t >> 6, lane = t & 63;
  const int cl = lane & 15, rg = lane >> 4;
  __shared__ __align__(16) bf16 Ps[64][200];

  const int qrow = q0 + w * 16 + cl;
  bf16x8 aq[2];
#pragma unroll
  for (int ks = 0; ks < 2; ++ks)
    aq[ks] = *reinterpret_cast<const bf16x8*>(Q + (size_t)qrow * 2048 + h * 64 + ks * 32 + rg * 8);

  f32x4 acc[12];
#pragma unroll
  for (int nf = 0; nf < 12; ++nf) acc[nf] = f32x4{0.f, 0.f, 0.f, 0.f};

#pragma unroll
  for (int nf = 0; nf < 12; ++nf) {
    int key = k0 + nf * 16 + cl;
    if (key < 0) key = 0;
#pragma unroll
    for (int ks = 0; ks < 2; ++ks) {
      bf16x8 bk = *reinterpret_cast<const bf16x8*>(Kb + (size_t)key * 512 + hk * 64 + ks * 32 + rg * 8);
      acc[nf] = __builtin_amdgcn_mfma_f32_16x16x32_bf16(aq[ks], bk, acc[nf], 0, 0, 0);
    }
  }

  const float sinkv = sinks[h];
  const float scale = 0.125f;
#pragma unroll
  for (int r = 0; r < 4; ++r) {
    const int rowb = w * 16 + rg * 4 + r;
    int cmin = rowb;
    if (128 - q0 > cmin) cmin = 128 - q0;
    const int cmax = rowb + 128;
    float m = sinkv;
    float pv[12];
#pragma unroll
    for (int nf = 0; nf < 12; ++nf) {
      int cc = nf * 16 + cl;
      float lv = (cc >= cmin && cc <= cmax) ? acc[nf][r] * scale : -INFINITY;
      pv[nf] = lv;
      m = fmaxf(m, lv);
    }
#pragma unroll
    for (int off = 1; off < 16; off <<= 1)
      m = fmaxf(m, __shfl_xor(m, off, 64));
    float sum = 0.f;
#pragma unroll
    for (int nf = 0; nf < 12; ++nf) {
      float p = __expf(pv[nf] - m);
      pv[nf] = p;
      sum += p;
    }
#pragma unroll
    for (int off = 1; off < 16; off <<= 1)
      sum += __shfl_xor(sum, off, 64);
    sum += __expf(sinkv - m);
    const float inv = 1.f / sum;
#pragma unroll
    for (int nf = 0; nf < 12; ++nf)
      Ps[rowb][nf * 16 + cl] = __float2bfloat16(pv[nf] * inv);
  }

  __syncthreads();

  f32x4 oacc[4];
#pragma unroll
  for (int j = 0; j < 4; ++j) oacc[j] = f32x4{0.f, 0.f, 0.f, 0.f};
#pragma unroll
  for (int ks = 0; ks < 6; ++ks) {
    bf16x8 pa = *reinterpret_cast<const bf16x8*>(&Ps[w * 16 + cl][ks * 32 + rg * 8]);
    int key = k0 + ks * 32 + rg * 8;
    if (key < 0) key = 0;
#pragma unroll
    for (int j = 0; j < 4; ++j) {
      bf16x8 bv = *reinterpret_cast<const bf16x8*>(Vt + ((size_t)hk * 64 + j * 16 + cl) * 2048 + key);
      oacc[j] = __builtin_amdgcn_mfma_f32_16x16x32_bf16(pa, bv, oacc[j], 0, 0, 0);
    }
  }

#pragma unroll
  for (int j = 0; j < 4; ++j)
#pragma unroll
    for (int r = 0; r < 4; ++r) {
      int gr = q0 + w * 16 + rg * 4 + r;
      int gc = h * 64 + j * 16 + cl;
      aout[(size_t)gr * 2048 + gc] = __float2bfloat16(oacc[j][r]);
    }
}

// ---------------- launch ----------------
extern "C" void kernel_launch(void* const* d_in, const int* in_sizes, int n_in,
                              void* d_out, int out_size, void* d_ws, size_t ws_size,
                              hipStream_t stream) {
  const float* x     = (const float*)d_in[0];
  const float* w1    = (const float*)d_in[1];
  const float* b1    = (const float*)d_in[2];
  const float* w2    = (const float*)d_in[3];
  const float* b2    = (const float*)d_in[4];
  const float* sinks = (const float*)d_in[5];
  const float* cosT  = (const float*)d_in[6];
  const float* sinT  = (const float*)d_in[7];
  float* out = (float*)d_out;

  char* ws = (char*)d_ws;
  bf16* xb   = (bf16*)(ws);                  // [2048][2048] 8 MB
  bf16* w1t  = (bf16*)(ws + 8388608);        // [3072][2048] 12 MB
  bf16* w2t  = (bf16*)(ws + 20971520);       // [2048][2048] 8 MB
  bf16* qbuf = (bf16*)(ws + 29360128);       // [2048][2048] 8 MB
  bf16* kbuf = (bf16*)(ws + 37748736);       // [2048][512]  2 MB
  bf16* vt   = (bf16*)(ws + 39845888);       // [512][2048]  2 MB
  bf16* attn = (bf16*)(ws + 41943040);       // [2048][2048] 8 MB
  (void)in_sizes; (void)n_in; (void)out_size; (void)ws_size;

  f32_to_bf16_kernel<<<4096, 256, 0, stream>>>(x, xb, 1048576);
  transpose_to_bf16_kernel<<<dim3(96, 64), 256, 0, stream>>>(w1, w1t, 2048, 3072);
  transpose_to_bf16_kernel<<<dim3(64, 64), 256, 0, stream>>>(w2, w2t, 2048, 2048);
  gemm1_kernel<<<256, 512, 122880, stream>>>(xb, w1t, b1, qbuf, kbuf, vt);
  rope_kernel<32, 7><<<1024, 256, 0, stream>>>(qbuf, cosT, sinT);
  rope_kernel<8, 5><<<256, 256, 0, stream>>>(kbuf, cosT, sinT);
  attn_kernel<<<dim3(32, 32), 256, 0, stream>>>(qbuf, kbuf, vt, sinks, attn);
  gemm2_kernel<<<256, 512, 98304, stream>>>(attn, w2t, b2, out);
}